// Round 8
// baseline (5512.883 us; speedup 1.0000x reference)
//
#include <hip/hip_runtime.h>
#include <hip/hip_bf16.h>

#define TT 512
#define BB 128
#define II 256
#define HH 512
#define OO 256

#define NGB 8     // batch groups
#define NGN 16    // N-slices per group
#define NS  32    // hidden cols per slice

#define PRED_SZ (TT*OO)

typedef __attribute__((ext_vector_type(8))) short bf16x8;
typedef __attribute__((ext_vector_type(4))) float f32x4;
typedef __attribute__((ext_vector_type(4))) int   i32x4;

// workspace layout (bytes)
#define WS_F2   0                        // flag2[8][32] int (layer1 posts h1 consumption)
#define WS_H1   2048                     // ring4 tagged words: [4][BB][HH] u32 = 1 MB
#define WS_H2   (WS_H1 + 4*BB*HH*4)      // ring4 tagged words: [4][BB][HH] u32 = 1 MB
#define WS_SAVE (WS_H2 + 4*BB*HH*4)      // [TT][HH] f32 = 1 MB (fully overwritten)
#define WS_ZERO WS_SAVE                  // zero flags + both tagged rings each launch

// tagged word: bits[31:16] = bf16(value) (RNE, rounded ONCE at produce)
//              bits[7:0]   = generation tag; bits[15:8] = 0

__device__ __forceinline__ ushort f2bf(float f) {
  union { float f; unsigned u; } v; v.f = f;
  unsigned u = v.u;
  return (ushort)((u + 0x7FFFu + ((u >> 16) & 1u)) >> 16);   // RNE
}

__device__ __forceinline__ float fast_tanh(float x) {
  float cx = fminf(fmaxf(x, -30.f), 30.f);
  float t  = __builtin_amdgcn_exp2f(cx * 2.885390081777927f);  // e^(2x)
  return (t - 1.f) * __builtin_amdgcn_rcpf(t + 1.f);
}

// ---- IF$-coherent primitives (round-2/6 proven: sc0 sc1 both ways) ----
__device__ __forceinline__ i32x4 ld16f(const int* p) {
  i32x4 r;
  asm volatile("global_load_dwordx4 %0, %1, off sc0 sc1" : "=v"(r) : "v"(p) : "memory");
  return r;
}
__device__ __forceinline__ f32x4 ld16g(const float* p) {   // plain cached load (x)
  f32x4 r;
  asm volatile("global_load_dwordx4 %0, %1, off" : "=v"(r) : "v"(p));
  return r;
}
__device__ __forceinline__ void st16(int* p, i32x4 v) {
  asm volatile("global_store_dwordx4 %0, %1, off sc0 sc1" :: "v"(p), "v"(v) : "memory");
}
__device__ __forceinline__ void st_flag(int* p, int v) {
  asm volatile("global_store_dword %0, %1, off sc0 sc1" :: "v"(p), "v"(v) : "memory");
}
__device__ __forceinline__ int ld_flag(const int* p) {
  int r;
  asm volatile("global_load_dword %0, %1, off sc0 sc1\n\ts_waitcnt vmcnt(0)"
               : "=v"(r) : "v"(p) : "memory");
  return r;
}
#define WAIT_VM(N) asm volatile("s_waitcnt vmcnt(" #N ")" ::: "memory")

// one bf16x8 fragment from 8 tagged words: shorts[i] = hi16(word_i). Exact (no re-round).
// v_perm_b32: D.b0..1 = S1.b2..3 (=w_even hi16), D.b2..3 = S0.b2..3 (=w_odd hi16)
__device__ __forceinline__ bf16x8 fragw(const i32x4* a, int q) {
  const i32x4 lo = a[2*q], hi = a[2*q+1];
  i32x4 r;
  r[0] = (int)__builtin_amdgcn_perm((unsigned)lo[1], (unsigned)lo[0], 0x07060302u);
  r[1] = (int)__builtin_amdgcn_perm((unsigned)lo[3], (unsigned)lo[2], 0x07060302u);
  r[2] = (int)__builtin_amdgcn_perm((unsigned)hi[1], (unsigned)hi[0], 0x07060302u);
  r[3] = (int)__builtin_amdgcn_perm((unsigned)hi[3], (unsigned)hi[2], 0x07060302u);
  return __builtin_bit_cast(bf16x8, r);
}

__global__ __launch_bounds__(256, 1) void rnn_scan_kernel(
    const float* __restrict__ x,
    const float* __restrict__ Wih0, const float* __restrict__ bih0,
    const float* __restrict__ Whh0, const float* __restrict__ bhh0,
    const float* __restrict__ Wih1, const float* __restrict__ bih1,
    const float* __restrict__ Whh1, const float* __restrict__ bhh1,
    float* __restrict__ out, char* __restrict__ ws)
{
  // packed W fragments (consumed as MFMA *A* operand):
  // unit u (0..111) = {Wih0: 0..15, Whh0: 16..47, Wih1: 48..79, Whh1: 80..111}
  __shared__ ushort ldsW[112*64*8];        // 112 KiB
  __shared__ float bias0[NS];
  __shared__ float bias1[NS];

  int*   flag2  = (int*)(ws + WS_F2);
  int*   h1f    = (int*)(ws + WS_H1);
  int*   h2f    = (int*)(ws + WS_H2);
  float* h2save = (float*)(ws + WS_SAVE);

  const int tid  = threadIdx.x;
  const int bid  = blockIdx.x;
  const int gb   = bid & 7;                // batch group
  const int gn   = bid >> 3;               // N-slice
  const int n0   = gn * NS;
  const int lane = tid & 63;

  // ---- one-time: pack weight slices (fp32 global -> bf16 LDS, fragment order) ----
  {
    const int q = tid >> 6;
    #pragma unroll 1
    for (int u = 0; u < 112; ++u) {
      const float* Wsrc; int Km; int ul;
      if (u < 16)      { Wsrc = Wih0; Km = II; ul = u; }
      else if (u < 48) { Wsrc = Whh0; Km = HH; ul = u - 16; }
      else if (u < 80) { Wsrc = Wih1; Km = HH; ul = u - 48; }
      else             { Wsrc = Whh1; Km = HH; ul = u - 80; }
      const int nk  = Km >> 5;
      const int ttl = ul / nk;
      const int kk  = ul - ttl*nk;
      const int n   = n0 + ttl*16 + (lane & 15);
      const int k   = kk*32 + (lane >> 4)*8 + q*2;
      const float2 wv = *(const float2*)(Wsrc + (size_t)n*Km + k);
      ushort2 b2; b2.x = f2bf(wv.x); b2.y = f2bf(wv.y);
      *(ushort2*)&ldsW[(u*64 + lane)*8 + q*2] = b2;
    }
    if (tid < NS) {
      bias0[tid] = bih0[n0+tid] + bhh0[n0+tid];
      bias1[tid] = bih1[n0+tid] + bhh1[n0+tid];
    }
  }
  __syncthreads();

  const int w     = tid >> 6;
  const int ttile = w & 1;                 // 16-col tile within the 32-col slice
  const int layer = w >> 1;                // waves 0,1 -> layer0; 2,3 -> layer1
  const int kq    = lane >> 4;
  const int c     = lane & 15;
  const int rowg  = gb*16 + c;             // batch row
  const int fl32  = lane & 31;
  const int nn    = ttile*16 + kq*4;       // first n-col within slice
  int* f2g = flag2 + gb*32;
  const int myf = gn*2 + ttile;

  if (layer == 0) {
    // ======== layer 0 self-chain: h1[p] = tanh(x[p] Wih0^T + h1[p-1] Whh0^T + b) ========
    f32x4 xacc = {0.f,0.f,0.f,0.f};
    {   // prologue: x-partial for p=0 (proven r6 path: f2bf scalar pack)
      const float* xp = x + (size_t)rowg*II + kq*8;
      f32x4 xv[16];
      #pragma unroll
      for (int kk = 0; kk < 8; ++kk) {
        xv[2*kk]   = ld16g(xp + kk*32);
        xv[2*kk+1] = ld16g(xp + kk*32 + 4);
      }
      WAIT_VM(0);
      __builtin_amdgcn_sched_barrier(0);
      #pragma unroll
      for (int kk = 0; kk < 8; ++kk) {
        bf16x8 a;
        #pragma unroll
        for (int j = 0; j < 4; ++j) {
          a[j]   = (short)f2bf(xv[2*kk][j]);
          a[j+4] = (short)f2bf(xv[2*kk+1][j]);
        }
        const bf16x8 wf = *(const bf16x8*)&ldsW[((ttile*8 + kk)*64 + lane)*8];
        xacc = __builtin_amdgcn_mfma_f32_16x16x32_bf16(wf, a, xacc, 0, 0, 0);
      }
    }

    int vf2 = 0;
    for (int p = 0; p < TT; ++p) {
      i32x4 af[32];
      if (p >= 1) {
        // ---- tagged data poll: the load IS the flag ----
        const int* ap = h1f + ((size_t)((p-1)&3)*BB + rowg)*HH + kq*8;
        const int expl = p & 255;
        const int* f2p = f2g + fl32;
        for (;;) {
          #pragma unroll
          for (int kk = 0; kk < 16; ++kk) {
            af[2*kk]   = ld16f(ap + kk*32);
            af[2*kk+1] = ld16f(ap + kk*32 + 4);
          }
          int f2v = vf2;
          if (p >= 4) {
            asm volatile("global_load_dword %0, %1, off sc0 sc1" : "=v"(f2v) : "v"(f2p) : "memory");
          }
          WAIT_VM(0);
          __builtin_amdgcn_sched_barrier(0);
          int bad = 0;
          #pragma unroll
          for (int q = 0; q < 32; ++q)
            bad |= (af[q][0]^expl) | (af[q][1]^expl) | (af[q][2]^expl) | (af[q][3]^expl);
          vf2 = f2v;
          if (__all((bad & 255) == 0)) break;
          __builtin_amdgcn_s_sleep(1);
        }
      }
      f32x4 ac1 = {0.f,0.f,0.f,0.f}, ac2 = {0.f,0.f,0.f,0.f};
      if (p >= 1) {
        #pragma unroll
        for (int kk = 0; kk < 8; ++kk) {
          const bf16x8 a0 = fragw(af, kk);
          const bf16x8 a1 = fragw(af, kk+8);
          const bf16x8 b0 = *(const bf16x8*)&ldsW[((16 + ttile*16 + kk)*64 + lane)*8];
          const bf16x8 b1 = *(const bf16x8*)&ldsW[((16 + ttile*16 + kk + 8)*64 + lane)*8];
          ac1 = __builtin_amdgcn_mfma_f32_16x16x32_bf16(b0, a0, ac1, 0, 0, 0);
          ac2 = __builtin_amdgcn_mfma_f32_16x16x32_bf16(b1, a1, ac2, 0, 0, 0);
        }
      }
      const float v0 = fast_tanh(xacc[0] + ac1[0] + ac2[0] + bias0[nn+0]);
      const float v1 = fast_tanh(xacc[1] + ac1[1] + ac2[1] + bias0[nn+1]);
      const float v2 = fast_tanh(xacc[2] + ac1[2] + ac2[2] + bias0[nn+2]);
      const float v3 = fast_tanh(xacc[3] + ac1[3] + ac2[3] + bias0[nn+3]);
      // ring-4 gate: layer1 must have consumed h1[p-4] (f2 >= p-3)
      if (p >= 4 && !__all(vf2 >= p-3)) {
        do { vf2 = ld_flag(f2g + fl32); } while (!__all(vf2 >= p-3));
      }
      // next-phase x loads BEFORE the store (in-order vmcnt: WAIT_VM(1) frees loads, not the store)
      const int pn = (p+1 < TT) ? (p+1) : (TT-1);
      f32x4 xv[16];
      {
        const float* xp = x + ((size_t)pn*BB + rowg)*II + kq*8;
        #pragma unroll
        for (int kk = 0; kk < 8; ++kk) {
          xv[2*kk]   = ld16g(xp + kk*32);
          xv[2*kk+1] = ld16g(xp + kk*32 + 4);
        }
      }
      // tagged store of h1[p]: word = bf16(v)<<16 | tag  (round ONCE, exact at consume)
      const int tg = (p+1) & 255;
      i32x4 d;
      d[0] = ((int)(unsigned)f2bf(v0) << 16) | tg;
      d[1] = ((int)(unsigned)f2bf(v1) << 16) | tg;
      d[2] = ((int)(unsigned)f2bf(v2) << 16) | tg;
      d[3] = ((int)(unsigned)f2bf(v3) << 16) | tg;
      st16(h1f + (size_t)(p&3)*BB*HH + (size_t)rowg*HH + n0 + nn, d);
      WAIT_VM(1);                          // 16 x loads retired; store stays in flight
      __builtin_amdgcn_sched_barrier(0);
      // x-pack + x-MFMAs for p+1 under the shadow of store visibility
      f32x4 xn = {0.f,0.f,0.f,0.f};
      #pragma unroll
      for (int kk = 0; kk < 8; ++kk) {
        bf16x8 a;
        #pragma unroll
        for (int j = 0; j < 4; ++j) {
          a[j]   = (short)f2bf(xv[2*kk][j]);
          a[j+4] = (short)f2bf(xv[2*kk+1][j]);
        }
        const bf16x8 wf = *(const bf16x8*)&ldsW[((ttile*8 + kk)*64 + lane)*8];
        xn = __builtin_amdgcn_mfma_f32_16x16x32_bf16(wf, a, xn, 0, 0, 0);
      }
      xacc = xn;
      if (p == TT-1) {
        *(f32x4*)&out[PRED_SZ + (size_t)rowg*HH + n0 + nn] = (f32x4){v0,v1,v2,v3};  // h_final[0]
      }
    }
  } else {
    // ======== layer 1: h2[p-1] = tanh(h1[p-1] Wih1^T + h2[p-2] Whh1^T + b) ========
    for (int p = 1; p <= TT; ++p) {
      // poll h2[p-2] (ring4, slot (p-2)&3): zeros (tag 0) = h2[-1] at p=1 ✓
      bf16x8 fa2[16];
      {
        i32x4 a2[32];
        const int* a2p = h2f + ((size_t)((p+2)&3)*BB + rowg)*HH + kq*8;  // (p-2)&3
        const int expl = (p-1) & 255;
        for (;;) {
          #pragma unroll
          for (int kk = 0; kk < 16; ++kk) {
            a2[2*kk]   = ld16f(a2p + kk*32);
            a2[2*kk+1] = ld16f(a2p + kk*32 + 4);
          }
          WAIT_VM(0);
          __builtin_amdgcn_sched_barrier(0);
          int bad = 0;
          #pragma unroll
          for (int q = 0; q < 32; ++q)
            bad |= (a2[q][0]^expl) | (a2[q][1]^expl) | (a2[q][2]^expl) | (a2[q][3]^expl);
          if (__all((bad & 255) == 0)) break;
          __builtin_amdgcn_s_sleep(1);
        }
        #pragma unroll
        for (int kk = 0; kk < 16; ++kk) fa2[kk] = fragw(a2, kk);
      }
      // poll h1[p-1] (the fresh one)
      i32x4 af[32];
      {
        const int* ap = h1f + ((size_t)((p-1)&3)*BB + rowg)*HH + kq*8;
        const int expl = p & 255;
        for (;;) {
          #pragma unroll
          for (int kk = 0; kk < 16; ++kk) {
            af[2*kk]   = ld16f(ap + kk*32);
            af[2*kk+1] = ld16f(ap + kk*32 + 4);
          }
          WAIT_VM(0);
          __builtin_amdgcn_sched_barrier(0);
          int bad = 0;
          #pragma unroll
          for (int q = 0; q < 32; ++q)
            bad |= (af[q][0]^expl) | (af[q][1]^expl) | (af[q][2]^expl) | (af[q][3]^expl);
          if (__all((bad & 255) == 0)) break;
          __builtin_amdgcn_s_sleep(1);
        }
      }
      if (lane == 0) st_flag(&f2g[myf], p);   // h1[p-1] consumed (in regs)

      f32x4 ac1 = {0.f,0.f,0.f,0.f}, ac2 = {0.f,0.f,0.f,0.f};
      f32x4 ac3 = {0.f,0.f,0.f,0.f}, ac4 = {0.f,0.f,0.f,0.f};
      #pragma unroll
      for (int kk = 0; kk < 8; ++kk) {
        const bf16x8 a0 = fragw(af, kk);
        const bf16x8 a1 = fragw(af, kk+8);
        const bf16x8 b0 = *(const bf16x8*)&ldsW[((48 + ttile*16 + kk)*64 + lane)*8];
        const bf16x8 b1 = *(const bf16x8*)&ldsW[((48 + ttile*16 + kk + 8)*64 + lane)*8];
        const bf16x8 b2 = *(const bf16x8*)&ldsW[((80 + ttile*16 + kk)*64 + lane)*8];
        const bf16x8 b3 = *(const bf16x8*)&ldsW[((80 + ttile*16 + kk + 8)*64 + lane)*8];
        ac1 = __builtin_amdgcn_mfma_f32_16x16x32_bf16(b0, a0, ac1, 0, 0, 0);
        ac2 = __builtin_amdgcn_mfma_f32_16x16x32_bf16(b1, a1, ac2, 0, 0, 0);
        ac3 = __builtin_amdgcn_mfma_f32_16x16x32_bf16(b2, fa2[kk],   ac3, 0, 0, 0);
        ac4 = __builtin_amdgcn_mfma_f32_16x16x32_bf16(b3, fa2[kk+8], ac4, 0, 0, 0);
      }
      const float v0 = fast_tanh(ac1[0] + ac2[0] + ac3[0] + ac4[0] + bias1[nn+0]);
      const float v1 = fast_tanh(ac1[1] + ac2[1] + ac3[1] + ac4[1] + bias1[nn+1]);
      const float v2 = fast_tanh(ac1[2] + ac2[2] + ac3[2] + ac4[2] + bias1[nn+2]);
      const float v3 = fast_tanh(ac1[3] + ac2[3] + ac3[3] + ac4[3] + bias1[nn+3]);
      const int tg = p & 255;                // tag of h2[p-1]
      i32x4 d;
      d[0] = ((int)(unsigned)f2bf(v0) << 16) | tg;
      d[1] = ((int)(unsigned)f2bf(v1) << 16) | tg;
      d[2] = ((int)(unsigned)f2bf(v2) << 16) | tg;
      d[3] = ((int)(unsigned)f2bf(v3) << 16) | tg;
      st16(h2f + (size_t)((p-1)&3)*BB*HH + (size_t)rowg*HH + n0 + nn, d);
      if (rowg == BB-1) {
        *(f32x4*)&h2save[(size_t)(p-1)*HH + n0 + nn] = (f32x4){v0,v1,v2,v3};   // row-127 trajectory
      }
      if (p == TT) {
        *(f32x4*)&out[PRED_SZ + BB*HH + (size_t)rowg*HH + n0 + nn] = (f32x4){v0,v1,v2,v3};  // h_final[1]
      }
    }
  }
}

__global__ __launch_bounds__(256) void rnn_pred_kernel(
    const float* __restrict__ Wfc, const float* __restrict__ bfc,
    const float* __restrict__ h2save, float* __restrict__ out)
{
  __shared__ float hs[HH];
  const int t = blockIdx.x;
  for (int i = threadIdx.x; i < HH; i += 256) hs[i] = h2save[(size_t)t*HH + i];
  __syncthreads();
  const int o = threadIdx.x;
  const f32x4* wr = (const f32x4*)(Wfc + (size_t)o*HH);
  f32x4 s = {0.f,0.f,0.f,0.f};
  #pragma unroll 8
  for (int k = 0; k < HH/4; ++k) {
    const f32x4 wv = wr[k];
    const f32x4 hv = *(const f32x4*)&hs[4*k];
    s += wv * hv;
  }
  out[(size_t)t*OO + o] = bfc[o] + s[0] + s[1] + s[2] + s[3];
}

extern "C" void kernel_launch(void* const* d_in, const int* in_sizes, int n_in,
                              void* d_out, int out_size, void* d_ws, size_t ws_size,
                              hipStream_t stream) {
  const float* x    = (const float*)d_in[0];
  const float* Wih0 = (const float*)d_in[1];
  const float* bih0 = (const float*)d_in[2];
  const float* Whh0 = (const float*)d_in[3];
  const float* bhh0 = (const float*)d_in[4];
  const float* Wih1 = (const float*)d_in[5];
  const float* bih1 = (const float*)d_in[6];
  const float* Whh1 = (const float*)d_in[7];
  const float* bhh1 = (const float*)d_in[8];
  const float* Wfc  = (const float*)d_in[9];
  const float* bfc  = (const float*)d_in[10];
  float* out = (float*)d_out;
  char*  ws  = (char*)d_ws;

  // zero flags + both tagged rings every launch (tags must start at generation 0)
  hipMemsetAsync(ws, 0, WS_ZERO, stream);

  rnn_scan_kernel<<<NGB*NGN, 256, 0, stream>>>(x, Wih0, bih0, Whh0, bhh0,
                                               Wih1, bih1, Whh1, bhh1, out, ws);
  rnn_pred_kernel<<<TT, 256, 0, stream>>>(Wfc, bfc, (const float*)(ws + WS_SAVE), out);
}